// Round 19
// baseline (448.873 us; speedup 1.0000x reference)
//
#include <hip/hip_runtime.h>
#include <float.h>

#define N_NODES 30000
#define N_EDGES 400000
#define N_TOT   430000
#define HID     128
#define NH      4
#define HC      512
#define NL      3
#define NG      64
#define NEG_SLOPE 0.2f
#define BN_EPS 1e-5f
#define POOL_CHUNK 32
#define LDA_PAD 136
#define SCAN_NB ((N_NODES + 1023) / 1024)   // 30

typedef __attribute__((ext_vector_type(8))) short bf16x8;
typedef __attribute__((ext_vector_type(4))) float f32x4;

__device__ __forceinline__ float atomAddF(float* p, float v) { return unsafeAtomicAdd(p, v); }

__device__ __forceinline__ unsigned encf(float x) {
  unsigned u = __float_as_uint(x);
  return (u & 0x80000000u) ? ~u : (u | 0x80000000u);
}
__device__ __forceinline__ float decf(unsigned u) {
  return (u & 0x80000000u) ? __uint_as_float(u ^ 0x80000000u) : __uint_as_float(~u);
}
__device__ __forceinline__ unsigned short f2bf(float f) {   // RNE
  unsigned u = __float_as_uint(f);
  u += 0x7FFFu + ((u >> 16) & 1u);
  return (unsigned short)(u >> 16);
}
__device__ __forceinline__ float bf2f(unsigned short s) {
  return __uint_as_float(((unsigned)s) << 16);
}

__device__ __forceinline__ void accum_edge(float acc[4][4],
                                           float& d0, float& d1, float& d2, float& d3,
                                           float4 ex, ushort4 v) {
  float f0 = bf2f(v.x), f1 = bf2f(v.y), f2 = bf2f(v.z), f3 = bf2f(v.w);
  d0 += ex.x; d1 += ex.y; d2 += ex.z; d3 += ex.w;
  acc[0][0] = fmaf(ex.x, f0, acc[0][0]); acc[0][1] = fmaf(ex.x, f1, acc[0][1]);
  acc[0][2] = fmaf(ex.x, f2, acc[0][2]); acc[0][3] = fmaf(ex.x, f3, acc[0][3]);
  acc[1][0] = fmaf(ex.y, f0, acc[1][0]); acc[1][1] = fmaf(ex.y, f1, acc[1][1]);
  acc[1][2] = fmaf(ex.y, f2, acc[1][2]); acc[1][3] = fmaf(ex.y, f3, acc[1][3]);
  acc[2][0] = fmaf(ex.z, f0, acc[2][0]); acc[2][1] = fmaf(ex.z, f1, acc[2][1]);
  acc[2][2] = fmaf(ex.z, f2, acc[2][2]); acc[2][3] = fmaf(ex.z, f3, acc[2][3]);
  acc[3][0] = fmaf(ex.w, f0, acc[3][0]); acc[3][1] = fmaf(ex.w, f1, acc[3][1]);
  acc[3][2] = fmaf(ex.w, f2, acc[3][2]); acc[3][3] = fmaf(ex.w, f3, acc[3][3]);
}

// ---------------- attention projection precompute ----------------
__global__ void prep_att_kernel(const float* __restrict__ W, const float* __restrict__ att_src,
                                const float* __restrict__ att_dst, const float* __restrict__ We,
                                const float* __restrict__ att_e,
                                float* __restrict__ wsrc, float* __restrict__ wdst,
                                float* __restrict__ weatt) {
  int l = blockIdx.x, t = threadIdx.x;   // 128 threads
  for (int h = 0; h < NH; ++h) {
    const float* as = att_src + (size_t)(l*NH + h)*HID;
    const float* ad = att_dst + (size_t)(l*NH + h)*HID;
    const float* wr = W + (size_t)(l*HID + t)*HC + h*HID;
    float s = 0.f, d = 0.f;
    for (int c = 0; c < HID; ++c) { float w = wr[c]; s += w*as[c]; d += w*ad[c]; }
    wsrc[(l*HID + t)*NH + h] = s;
    wdst[(l*HID + t)*NH + h] = d;
  }
  if (t < 3) {
    for (int h = 0; h < NH; ++h) {
      const float* ae = att_e + (size_t)(l*NH + h)*HID;
      const float* wr = We + (size_t)(l*3 + t)*HC + h*HID;
      float s = 0.f;
      for (int c = 0; c < HID; ++c) s += wr[c]*ae[c];
      weatt[(l*3 + t)*NH + h] = s;
    }
  }
}

// Packed MFMA B-fragments for gemm2
__global__ void prep_wt2_kernel(const float* __restrict__ W, unsigned short* __restrict__ Wt2P) {
  int l = blockIdx.y;
  int idx = blockIdx.x*256 + threadIdx.x;   // over 65536
  int j    = idx & 7;
  int lane = (idx >> 3) & 63;
  int nf   = (idx >> 9) & 7;
  int kk   = idx >> 12;
  int co = nf*16 + (lane & 15);
  int k  = kk*32 + (lane >> 4)*8 + j;
  int h = k >> 7, ci = k & 127;
  Wt2P[(size_t)l*65536 + idx] = f2bf(0.25f * W[((size_t)l*HID + ci)*HC + h*128 + co]);
}

// node-MLP transposed bf16 weights
__global__ void prep_mlpw_kernel(const float* __restrict__ nw1, const float* __restrict__ nw2,
                                 unsigned short* __restrict__ wt1, unsigned short* __restrict__ wt2) {
  int t = blockIdx.x*256 + threadIdx.x;
  if (t < 64*128) {
    int n = t >> 7, k = t & 127;
    wt1[t] = f2bf(nw1[k*64 + n]);
  }
  if (t < 32*64) {
    int n = t >> 6, k = t & 63;
    wt2[t] = f2bf(nw2[k*32 + n]);
  }
}

// x -> bf16 (once)
__global__ void xconv_kernel(const float* __restrict__ x, unsigned short* __restrict__ hb16) {
  int i = blockIdx.x*256 + threadIdx.x;
  if (i >= N_NODES*HID/4) return;
  float4 v = *(const float4*)&x[(size_t)i*4];
  ushort4 o; o.x = f2bf(v.x); o.y = f2bf(v.y); o.z = f2bf(v.z); o.w = f2bf(v.w);
  *(ushort4*)&hb16[(size_t)i*4] = o;
}

// in-degree count
__global__ void deg_kernel(const int* __restrict__ ei, int* __restrict__ degi) {
  int e = blockIdx.x*blockDim.x + threadIdx.x;
  if (e >= N_EDGES) return;
  atomicAdd(&degi[ei[N_EDGES + e]], 1);
}

// ---------------- CSR build: two-phase multi-block exclusive scan ----------------
__global__ __launch_bounds__(1024) void scan1_kernel(const int* __restrict__ degi,
                                                     int* __restrict__ rowptr,
                                                     int* __restrict__ fill,
                                                     int* __restrict__ blocksum) {
  __shared__ int sh[1024];
  int b = blockIdx.x, t = threadIdx.x;
  int idx = b*1024 + t;
  int d = (idx < N_NODES) ? degi[idx] : 0;
  sh[t] = d;
  __syncthreads();
  for (int off = 1; off < 1024; off <<= 1) {
    int v = (t >= off) ? sh[t - off] : 0;
    __syncthreads();
    sh[t] += v;
    __syncthreads();
  }
  if (idx < N_NODES) {
    rowptr[idx] = sh[t] - d;
    fill[idx] = 0;
  }
  if (t == 1023) blocksum[b] = sh[1023];
}

__global__ __launch_bounds__(1024) void scan2_kernel(const int* __restrict__ blocksum,
                                                     int* __restrict__ rowptr) {
  int b = blockIdx.x, t = threadIdx.x;
  int off = 0;
  for (int i = 0; i < b; ++i) off += blocksum[i];
  int idx = b*1024 + t;
  if (idx < N_NODES && b > 0) rowptr[idx] += off;
  if (b == SCAN_NB - 1 && t == 1023)
    rowptr[N_NODES] = off + blocksum[SCAN_NB - 1];
}

__global__ void csr_fill_kernel(const int* __restrict__ ei, const int* __restrict__ rowptr,
                                int* __restrict__ fill, int* __restrict__ csr_src,
                                int* __restrict__ csr_pos, int* __restrict__ csr_eid) {
  int e = blockIdx.x*blockDim.x + threadIdx.x;
  if (e >= N_EDGES) return;
  int s = ei[e], d = ei[N_EDGES + e];
  int pos = rowptr[d] + atomicAdd(&fill[d], 1);
  csr_src[pos] = s;
  csr_pos[e] = pos;
  csr_eid[pos] = e;
}

// easum from CSR
__global__ void easum_kernel(const int* __restrict__ rowptr, const int* __restrict__ csr_eid,
                             const float* __restrict__ ea, float* __restrict__ easum) {
  int n = blockIdx.x*256 + threadIdx.x;
  if (n >= N_NODES) return;
  int p0 = rowptr[n], p1 = rowptr[n+1];
  float s0 = 0.f, s1 = 0.f, s2 = 0.f;
  for (int p = p0; p < p1; ++p) {
    int e = csr_eid[p];
    s0 += ea[e*3+0]; s1 += ea[e*3+1]; s2 += ea[e*3+2];
  }
  easum[n*3+0] = s0; easum[n*3+1] = s1; easum[n*3+2] = s2;
}

// ---------------- a_s/a_d from f32 input (layer 0 only) ----------------
__global__ __launch_bounds__(256) void asd_kernel(const float* __restrict__ hin,
                                                  const float* __restrict__ wsrcL,
                                                  const float* __restrict__ wdstL,
                                                  float* __restrict__ a_s, float* __restrict__ a_d) {
  int wid = (blockIdx.x*256 + threadIdx.x) >> 6;
  int lane = threadIdx.x & 63;
  if (wid >= N_NODES) return;
  float v0 = hin[(size_t)wid*HID + lane];
  float v1 = hin[(size_t)wid*HID + 64 + lane];
  float4 w0s = *(const float4*)&wsrcL[lane*4];
  float4 w1s = *(const float4*)&wsrcL[(64+lane)*4];
  float4 w0d = *(const float4*)&wdstL[lane*4];
  float4 w1d = *(const float4*)&wdstL[(64+lane)*4];
  float ps0 = v0*w0s.x + v1*w1s.x, ps1 = v0*w0s.y + v1*w1s.y;
  float ps2 = v0*w0s.z + v1*w1s.z, ps3 = v0*w0s.w + v1*w1s.w;
  float pd0 = v0*w0d.x + v1*w1d.x, pd1 = v0*w0d.y + v1*w1d.y;
  float pd2 = v0*w0d.z + v1*w1d.z, pd3 = v0*w0d.w + v1*w1d.w;
  #pragma unroll
  for (int off = 32; off > 0; off >>= 1) {
    ps0 += __shfl_xor(ps0, off); ps1 += __shfl_xor(ps1, off);
    ps2 += __shfl_xor(ps2, off); ps3 += __shfl_xor(ps3, off);
    pd0 += __shfl_xor(pd0, off); pd1 += __shfl_xor(pd1, off);
    pd2 += __shfl_xor(pd2, off); pd3 += __shfl_xor(pd3, off);
  }
  if (lane == 0) {
    *(float4*)&a_s[wid*4] = make_float4(ps0, ps1, ps2, ps3);
    *(float4*)&a_d[wid*4] = make_float4(pd0, pd1, pd2, pd3);
  }
}

// ---------------- edge pass ----------------
__global__ void edge_ex_kernel(const int* __restrict__ ei, const float* __restrict__ ea,
                               const float* __restrict__ easum, const int* __restrict__ rowptr,
                               const float* __restrict__ a_s, const float* __restrict__ a_d,
                               const float* __restrict__ weattL, const int* __restrict__ csr_pos,
                               float* __restrict__ excsr, float* __restrict__ exself) {
  int e = blockIdx.x*blockDim.x + threadIdx.x;
  if (e >= N_TOT) return;
  int s, d; float e0, e1, e2;
  if (e < N_EDGES) {
    s = ei[e]; d = ei[N_EDGES + e];
    e0 = ea[e*3+0]; e1 = ea[e*3+1]; e2 = ea[e*3+2];
  } else {
    int n = e - N_EDGES; s = n; d = n;
    float dg = (float)(rowptr[n+1] - rowptr[n]);
    float inv = 1.f / fmaxf(dg, 1.f);
    e0 = easum[n*3+0]*inv; e1 = easum[n*3+1]*inv; e2 = easum[n*3+2]*inv;
  }
  float4 as4 = *(const float4*)&a_s[s*4];
  float4 ad4 = *(const float4*)&a_d[d*4];
  float4 w0 = *(const float4*)&weattL[0];
  float4 w1 = *(const float4*)&weattL[4];
  float4 w2 = *(const float4*)&weattL[8];
  float raw0 = as4.x + ad4.x + e0*w0.x + e1*w1.x + e2*w2.x;
  float raw1 = as4.y + ad4.y + e0*w0.y + e1*w1.y + e2*w2.y;
  float raw2 = as4.z + ad4.z + e0*w0.z + e1*w1.z + e2*w2.z;
  float raw3 = as4.w + ad4.w + e0*w0.w + e1*w1.w + e2*w2.w;
  raw0 = raw0 > 0.f ? raw0 : NEG_SLOPE*raw0;
  raw1 = raw1 > 0.f ? raw1 : NEG_SLOPE*raw1;
  raw2 = raw2 > 0.f ? raw2 : NEG_SLOPE*raw2;
  raw3 = raw3 > 0.f ? raw3 : NEG_SLOPE*raw3;
  float4 exv = make_float4(__expf(raw0), __expf(raw1), __expf(raw2), __expf(raw3));
  if (e < N_EDGES) {
    *(float4*)&excsr[(size_t)csr_pos[e]*4] = exv;
  } else {
    *(float4*)&exself[(size_t)(e - N_EDGES)*4] = exv;
  }
}

// ---------------- CSR aggregation, COLUMN-SPLIT pass (64 cols per pass) ----------------
// Lane map: quarter q = lane>>4 owns edge slot q (4 edges/wave/iter), li = lane&15 owns
// cols coff + li*4 .. +4. Gathered working set per pass = N*64*2B = 3.8MB < 4MiB/XCD L2.
// Quarter-reduce via shfl_xor(16,32); quarter q writes head q's half-row.
// Pass with coff==0, block 0 also zeroes colsum/colsq for the following gemm2.
__global__ __launch_bounds__(256) void agg_half_kernel(const int* __restrict__ rowptr,
    const int* __restrict__ csr_src, const float* __restrict__ excsr,
    const float* __restrict__ exself, const unsigned short* __restrict__ hb16,
    unsigned short* __restrict__ g16, float* __restrict__ colsum, float* __restrict__ colsq,
    int coff) {
  if (coff == 0 && blockIdx.x == 0) {
    int tt = threadIdx.x;
    if (tt < 128) colsum[tt] = 0.f;
    else if (tt < 256) colsq[tt-128] = 0.f;
  }
  int wid = (blockIdx.x*256 + threadIdx.x) >> 6;
  int lane = threadIdx.x & 63;
  if (wid >= N_NODES) return;
  int q = lane >> 4, li = lane & 15;
  int c0 = coff + li*4;
  int p0 = rowptr[wid], p1 = rowptr[wid+1];
  float acc[4][4] = {};
  float den0 = 0.f, den1 = 0.f, den2 = 0.f, den3 = 0.f;
  if (q == 0) {   // self loop
    float4 ex = *(const float4*)&exself[(size_t)wid*4];
    ushort4 v = *(const ushort4*)&hb16[(size_t)wid*HID + c0];
    accum_edge(acc, den0, den1, den2, den3, ex, v);
  }
  int p = p0;
  for (; p + 8 <= p1; p += 8) {       // 2 edges per quarter, batched loads
    int pa = p + q, pb = p + 4 + q;
    int sa = csr_src[pa], sb = csr_src[pb];
    float4 ea = *(const float4*)&excsr[(size_t)pa*4];
    float4 eb = *(const float4*)&excsr[(size_t)pb*4];
    ushort4 va = *(const ushort4*)&hb16[(size_t)sa*HID + c0];
    ushort4 vb = *(const ushort4*)&hb16[(size_t)sb*HID + c0];
    accum_edge(acc, den0, den1, den2, den3, ea, va);
    accum_edge(acc, den0, den1, den2, den3, eb, vb);
  }
  for (; p + 4 <= p1; p += 4) {       // 1 edge per quarter
    int pe = p + q;
    int s = csr_src[pe];
    float4 ex = *(const float4*)&excsr[(size_t)pe*4];
    ushort4 v = *(const ushort4*)&hb16[(size_t)s*HID + c0];
    accum_edge(acc, den0, den1, den2, den3, ex, v);
  }
  if (p + q < p1) {                   // tail (quarters q < remaining)
    int pe = p + q;
    int s = csr_src[pe];
    float4 ex = *(const float4*)&excsr[(size_t)pe*4];
    ushort4 v = *(const ushort4*)&hb16[(size_t)s*HID + c0];
    accum_edge(acc, den0, den1, den2, den3, ex, v);
  }
  // reduce across quarters (every lane ends with the full sums)
  #pragma unroll
  for (int h = 0; h < 4; ++h)
    #pragma unroll
    for (int j = 0; j < 4; ++j) {
      acc[h][j] += __shfl_xor(acc[h][j], 16);
      acc[h][j] += __shfl_xor(acc[h][j], 32);
    }
  den0 += __shfl_xor(den0, 16); den0 += __shfl_xor(den0, 32);
  den1 += __shfl_xor(den1, 16); den1 += __shfl_xor(den1, 32);
  den2 += __shfl_xor(den2, 16); den2 += __shfl_xor(den2, 32);
  den3 += __shfl_xor(den3, 16); den3 += __shfl_xor(den3, 32);
  // quarter q writes head q's cols [c0, c0+4)  (static indexing per branch)
  ushort4 o;
  if (q == 0) {
    float iv = 1.f/den0;
    o.x=f2bf(acc[0][0]*iv); o.y=f2bf(acc[0][1]*iv); o.z=f2bf(acc[0][2]*iv); o.w=f2bf(acc[0][3]*iv);
  } else if (q == 1) {
    float iv = 1.f/den1;
    o.x=f2bf(acc[1][0]*iv); o.y=f2bf(acc[1][1]*iv); o.z=f2bf(acc[1][2]*iv); o.w=f2bf(acc[1][3]*iv);
  } else if (q == 2) {
    float iv = 1.f/den2;
    o.x=f2bf(acc[2][0]*iv); o.y=f2bf(acc[2][1]*iv); o.z=f2bf(acc[2][2]*iv); o.w=f2bf(acc[2][3]*iv);
  } else {
    float iv = 1.f/den3;
    o.x=f2bf(acc[3][0]*iv); o.y=f2bf(acc[3][1]*iv); o.z=f2bf(acc[3][2]*iv); o.w=f2bf(acc[3][3]*iv);
  }
  *(ushort4*)&g16[(size_t)wid*HC + q*128 + c0] = o;
}

// ---------------- gemm2: LDS-staged packed B + fused BN stats ----------------
#define MFMA16(a, b, c) __builtin_amdgcn_mfma_f32_16x16x32_bf16(a, b, c, 0, 0, 0)

__global__ __launch_bounds__(256) void gemm2_mfma_kernel(const unsigned short* __restrict__ g16,
                                                         const unsigned short* __restrict__ Wt2P,
                                                         float* __restrict__ C,
                                                         float* __restrict__ colsum,
                                                         float* __restrict__ colsq) {
  __shared__ unsigned short Bs[4*8*512];     // 32 KB
  __shared__ float cs_s[128], cq_s[128];
  int m0 = blockIdx.x * 64;
  int t = threadIdx.x;
  int wave = t >> 6, lane = t & 63;
  int mbase = m0 + wave * 16;
  int lrow = lane & 15;
  if (t < 128) { cs_s[t] = 0.f; cq_s[t] = 0.f; }
  int arow = mbase + lrow;
  const unsigned short* arp = g16 + (size_t)(arow < N_NODES ? arow : 0)*HC + (lane >> 4)*8;
  f32x4 acc[8] = {};
  for (int ph = 0; ph < 4; ++ph) {
    const bf16x8* src = (const bf16x8*)(Wt2P + ph*16384);
    __syncthreads();
    #pragma unroll
    for (int i = 0; i < 8; ++i)
      *(bf16x8*)&Bs[(t + i*256)*8] = src[t + i*256];
    __syncthreads();
    #pragma unroll
    for (int kk = 0; kk < 4; ++kk) {
      bf16x8 a = *(const bf16x8*)&arp[(ph*4 + kk)*32];
      #pragma unroll
      for (int nf = 0; nf < 8; ++nf) {
        bf16x8 b = *(const bf16x8*)&Bs[(kk*8 + nf)*512 + lane*8];
        acc[nf] = MFMA16(a, b, acc[nf]);
      }
    }
  }
  int orow = (lane >> 4) * 4, ocol = lane & 15;
  #pragma unroll
  for (int nf = 0; nf < 8; ++nf) {
    float s = 0.f, q = 0.f;
    #pragma unroll
    for (int r = 0; r < 4; ++r) {
      int gm = mbase + orow + r;
      float v = acc[nf][r];
      if (gm < N_NODES) {
        C[(size_t)gm*HID + nf*16 + ocol] = v;
        s += v; q += v*v;
      }
    }
    atomicAdd(&cs_s[nf*16 + ocol], s);
    atomicAdd(&cq_s[nf*16 + ocol], q);
  }
  __syncthreads();
  if (t < 128) {
    atomAddF(&colsum[t], cs_s[t]);
    atomAddF(&colsq[t], cq_s[t]);
  }
}

// ---------------- fused BN-apply + next-layer a_s/a_d ----------------
__global__ __launch_bounds__(256) void bnasd_kernel(const float* __restrict__ hpre,
    const float* __restrict__ colsum, const float* __restrict__ colsq,
    const float* __restrict__ gammaL, const float* __restrict__ betaL,
    const float* __restrict__ wsrcL, const float* __restrict__ wdstL,
    unsigned short* __restrict__ hb16, float* __restrict__ a_s, float* __restrict__ a_d) {
  int wid = (blockIdx.x*256 + threadIdx.x) >> 6;
  int lane = threadIdx.x & 63;
  if (wid >= N_NODES) return;
  const float invn = 1.f / (float)N_NODES;
  float v0 = hpre[(size_t)wid*HID + lane];
  float v1 = hpre[(size_t)wid*HID + 64 + lane];
  float mu0 = colsum[lane]*invn, mu1 = colsum[64+lane]*invn;
  float var0 = fmaxf(colsq[lane]*invn - mu0*mu0, 0.f);
  float var1 = fmaxf(colsq[64+lane]*invn - mu1*mu1, 0.f);
  float sc0 = gammaL[lane]*rsqrtf(var0 + BN_EPS), sh0 = betaL[lane] - mu0*sc0;
  float sc1 = gammaL[64+lane]*rsqrtf(var1 + BN_EPS), sh1 = betaL[64+lane] - mu1*sc1;
  v0 = fmaxf(fmaf(v0, sc0, sh0), 0.f);
  v1 = fmaxf(fmaf(v1, sc1, sh1), 0.f);
  hb16[(size_t)wid*HID + lane] = f2bf(v0);
  hb16[(size_t)wid*HID + 64 + lane] = f2bf(v1);
  float4 w0s = *(const float4*)&wsrcL[lane*4];
  float4 w1s = *(const float4*)&wsrcL[(64+lane)*4];
  float4 w0d = *(const float4*)&wdstL[lane*4];
  float4 w1d = *(const float4*)&wdstL[(64+lane)*4];
  float ps0 = v0*w0s.x + v1*w1s.x, ps1 = v0*w0s.y + v1*w1s.y;
  float ps2 = v0*w0s.z + v1*w1s.z, ps3 = v0*w0s.w + v1*w1s.w;
  float pd0 = v0*w0d.x + v1*w1d.x, pd1 = v0*w0d.y + v1*w1d.y;
  float pd2 = v0*w0d.z + v1*w1d.z, pd3 = v0*w0d.w + v1*w1d.w;
  #pragma unroll
  for (int off = 32; off > 0; off >>= 1) {
    ps0 += __shfl_xor(ps0, off); ps1 += __shfl_xor(ps1, off);
    ps2 += __shfl_xor(ps2, off); ps3 += __shfl_xor(ps3, off);
    pd0 += __shfl_xor(pd0, off); pd1 += __shfl_xor(pd1, off);
    pd2 += __shfl_xor(pd2, off); pd3 += __shfl_xor(pd3, off);
  }
  if (lane == 0) {
    *(float4*)&a_s[wid*4] = make_float4(ps0, ps1, ps2, ps3);
    *(float4*)&a_d[wid*4] = make_float4(pd0, pd1, pd2, pd3);
  }
}

// ---------------- final-layer BN apply -> bf16 only ----------------
__global__ void bnfinal_kernel(const float* __restrict__ hpre,
                               const float* __restrict__ colsum, const float* __restrict__ colsq,
                               const float* __restrict__ gammaL, const float* __restrict__ betaL,
                               unsigned short* __restrict__ hb16) {
  int i = blockIdx.x*blockDim.x + threadIdx.x;
  if (i >= N_NODES*HID/4) return;
  int c4 = (i*4) & 127;
  const float invn = 1.f / (float)N_NODES;
  float4 v = *(const float4*)&hpre[(size_t)i*4];
  float4 cs = *(const float4*)&colsum[c4];
  float4 cq = *(const float4*)&colsq[c4];
  float4 gm = *(const float4*)&gammaL[c4];
  float4 bt = *(const float4*)&betaL[c4];
  float mu, var, sc, sh;
  mu = cs.x*invn; var = fmaxf(cq.x*invn - mu*mu, 0.f); sc = gm.x*rsqrtf(var + BN_EPS); sh = bt.x - mu*sc;
  v.x = fmaxf(fmaf(v.x, sc, sh), 0.f);
  mu = cs.y*invn; var = fmaxf(cq.y*invn - mu*mu, 0.f); sc = gm.y*rsqrtf(var + BN_EPS); sh = bt.y - mu*sc;
  v.y = fmaxf(fmaf(v.y, sc, sh), 0.f);
  mu = cs.z*invn; var = fmaxf(cq.z*invn - mu*mu, 0.f); sc = gm.z*rsqrtf(var + BN_EPS); sh = bt.z - mu*sc;
  v.z = fmaxf(fmaf(v.z, sc, sh), 0.f);
  mu = cs.w*invn; var = fmaxf(cq.w*invn - mu*mu, 0.f); sc = gm.w*rsqrtf(var + BN_EPS); sh = bt.w - mu*sc;
  v.w = fmaxf(fmaf(v.w, sc, sh), 0.f);
  ushort4 o; o.x = f2bf(v.x); o.y = f2bf(v.y); o.z = f2bf(v.z); o.w = f2bf(v.w);
  *(ushort4*)&hb16[(size_t)i*4] = o;
}

// ---------------- node MLP (block 0 also inits pooling buffers) ----------------
__global__ __launch_bounds__(256) void nodemlp_kernel(const unsigned short* __restrict__ h16,
    const unsigned short* __restrict__ wt1, const float* __restrict__ b1,
    const unsigned short* __restrict__ wt2, const float* __restrict__ b2,
    const float* __restrict__ w3, const float* __restrict__ b3,
    float* __restrict__ out,
    float* __restrict__ gsum, float* __restrict__ gcnt, unsigned* __restrict__ gmaxenc) {
  __shared__ unsigned short As[128 * LDA_PAD];
  __shared__ unsigned short L1s[128 * 72];
  __shared__ float L2s[128 * 33];
  int m0 = blockIdx.x * 128;
  int t = threadIdx.x;
  if (blockIdx.x == 0) {
    for (int i = t; i < NG*HID; i += 256) { gsum[i] = 0.f; gmaxenc[i] = 0x00800000u; }
    if (t < NG) gcnt[t] = 0.f;
  }
  #pragma unroll
  for (int i = 0; i < 8; ++i) {
    int idx = t + i*256;
    int row = idx >> 4, k8 = (idx & 15) * 8;
    int gm = m0 + row;
    bf16x8 v = {};
    if (gm < N_NODES) v = *(const bf16x8*)&h16[(size_t)gm*HID + k8];
    *(bf16x8*)&As[row*LDA_PAD + k8] = v;
  }
  __syncthreads();
  int wave = t >> 6, lane = t & 63;
  int mbase = wave * 32;
  int lrow = lane & 15, lk = (lane >> 4) * 8;
  int orow = (lane >> 4) * 4, ocol = lane & 15;
  // layer 1
  f32x4 acc[2][4] = {};
  #pragma unroll
  for (int ks = 0; ks < 4; ++ks) {
    int k0 = ks * 32;
    bf16x8 a0 = *(const bf16x8*)&As[(mbase + lrow)*LDA_PAD + k0 + lk];
    bf16x8 a1 = *(const bf16x8*)&As[(mbase + 16 + lrow)*LDA_PAD + k0 + lk];
    #pragma unroll
    for (int nf = 0; nf < 4; ++nf) {
      bf16x8 b = *(const bf16x8*)&wt1[(size_t)(nf*16 + lrow)*HID + k0 + lk];
      acc[0][nf] = MFMA16(a0, b, acc[0][nf]);
      acc[1][nf] = MFMA16(a1, b, acc[1][nf]);
    }
  }
  #pragma unroll
  for (int mf = 0; mf < 2; ++mf)
    #pragma unroll
    for (int nf = 0; nf < 4; ++nf) {
      float bb = b1[nf*16 + ocol];
      #pragma unroll
      for (int r = 0; r < 4; ++r)
        L1s[(mbase + mf*16 + orow + r)*72 + nf*16 + ocol] = f2bf(fmaxf(acc[mf][nf][r] + bb, 0.f));
    }
  __syncthreads();
  // layer 2
  f32x4 acc2[2][2] = {};
  #pragma unroll
  for (int ks = 0; ks < 2; ++ks) {
    int k0 = ks * 32;
    bf16x8 a0 = *(const bf16x8*)&L1s[(mbase + lrow)*72 + k0 + lk];
    bf16x8 a1 = *(const bf16x8*)&L1s[(mbase + 16 + lrow)*72 + k0 + lk];
    #pragma unroll
    for (int nf = 0; nf < 2; ++nf) {
      bf16x8 b = *(const bf16x8*)&wt2[(size_t)(nf*16 + lrow)*64 + k0 + lk];
      acc2[0][nf] = MFMA16(a0, b, acc2[0][nf]);
      acc2[1][nf] = MFMA16(a1, b, acc2[1][nf]);
    }
  }
  #pragma unroll
  for (int mf = 0; mf < 2; ++mf)
    #pragma unroll
    for (int nf = 0; nf < 2; ++nf) {
      float bb = b2[nf*16 + ocol];
      #pragma unroll
      for (int r = 0; r < 4; ++r)
        L2s[(mbase + mf*16 + orow + r)*33 + nf*16 + ocol] = fmaxf(acc2[mf][nf][r] + bb, 0.f);
    }
  __syncthreads();
  // layer 3
  {
    int node = t >> 1, j = t & 1;
    int gm = m0 + node;
    if (gm < N_NODES) {
      float accv = b3[j];
      #pragma unroll
      for (int k = 0; k < 32; ++k)
        accv = fmaf(L2s[node*33 + k], w3[k*2 + j], accv);
      out[(size_t)gm*2 + j] = accv;
    }
  }
}

// ---------------- graph pooling (segmented over sorted batch, bf16 input) ----------------
__global__ __launch_bounds__(128) void pool_seg_kernel(const unsigned short* __restrict__ h16,
                                                       const int* __restrict__ batch,
                                                       float* __restrict__ gsum,
                                                       unsigned* __restrict__ gmaxenc,
                                                       float* __restrict__ gcnt) {
  int t = threadIdx.x;
  int r0 = blockIdx.x * POOL_CHUNK;
  int rend = min(r0 + POOL_CHUNK, N_NODES);
  if (r0 >= N_NODES) return;
  int gcur = batch[r0];
  float s = 0.f, m = -FLT_MAX;
  int cnt = 0;
  for (int r = r0; r < rend; ++r) {
    int g = batch[r];
    if (g != gcur) {
      atomAddF(&gsum[gcur*HID + t], s);
      atomicMax(&gmaxenc[gcur*HID + t], encf(m));
      if (t == 0) atomAddF(&gcnt[gcur], (float)cnt);
      gcur = g; s = 0.f; m = -FLT_MAX; cnt = 0;
    }
    float v = bf2f(h16[(size_t)r*HID + t]);
    s += v; m = fmaxf(m, v);
    ++cnt;
  }
  atomAddF(&gsum[gcur*HID + t], s);
  atomicMax(&gmaxenc[gcur*HID + t], encf(m));
  if (t == 0) atomAddF(&gcnt[gcur], (float)cnt);
}

// ---------------- graph MLP ----------------
__global__ __launch_bounds__(128) void graphmlp_kernel(const float* __restrict__ gsum,
    const unsigned* __restrict__ gmaxenc, const float* __restrict__ gcnt,
    const float* __restrict__ gw1, const float* __restrict__ gb1,
    const float* __restrict__ gw2, const float* __restrict__ gb2,
    const float* __restrict__ gw3, const float* __restrict__ gb3,
    float* __restrict__ out) {
  __shared__ float gr[256], h1[128], h2[64];
  int g = blockIdx.x, t = threadIdx.x;
  float cnt = fmaxf(gcnt[g], 1.f);
  gr[t] = gsum[g*HID + t] / cnt;
  gr[128 + t] = decf(gmaxenc[g*HID + t]);
  __syncthreads();
  float acc = gb1[t];
  for (int k = 0; k < 256; ++k) acc += gr[k]*gw1[k*HID + t];
  h1[t] = fmaxf(acc, 0.f);
  __syncthreads();
  if (t < 64) {
    float a2 = gb2[t];
    for (int k = 0; k < 128; ++k) a2 += h1[k]*gw2[k*64 + t];
    h2[t] = fmaxf(a2, 0.f);
  }
  __syncthreads();
  if (t < 2) {
    float a3 = gb3[t];
    for (int k = 0; k < 64; ++k) a3 += h2[k]*gw3[k*2 + t];
    out[N_NODES*2 + g*2 + t] = a3;
  }
}

extern "C" void kernel_launch(void* const* d_in, const int* in_sizes, int n_in,
                              void* d_out, int out_size, void* d_ws, size_t ws_size,
                              hipStream_t stream) {
  (void)in_sizes; (void)n_in; (void)out_size; (void)ws_size;
  const float* x       = (const float*)d_in[0];
  const int*   ei      = (const int*)d_in[1];
  const float* ea      = (const float*)d_in[2];
  const int*   batch   = (const int*)d_in[3];
  const float* W       = (const float*)d_in[4];
  const float* att_src = (const float*)d_in[5];
  const float* att_dst = (const float*)d_in[6];
  const float* We      = (const float*)d_in[7];
  const float* att_e   = (const float*)d_in[8];
  const float* gamma   = (const float*)d_in[10];
  const float* beta    = (const float*)d_in[11];
  const float* nw1 = (const float*)d_in[12]; const float* nb1 = (const float*)d_in[13];
  const float* nw2 = (const float*)d_in[14]; const float* nb2 = (const float*)d_in[15];
  const float* nw3 = (const float*)d_in[16]; const float* nb3 = (const float*)d_in[17];
  const float* gw1 = (const float*)d_in[18]; const float* gb1 = (const float*)d_in[19];
  const float* gw2 = (const float*)d_in[20]; const float* gb2 = (const float*)d_in[21];
  const float* gw3 = (const float*)d_in[22]; const float* gb3 = (const float*)d_in[23];
  float* out = (float*)d_out;

  float* p = (float*)d_ws;
  unsigned short* g16 = (unsigned short*)p; p += (size_t)N_NODES*HC/2;
  unsigned short* hb16= (unsigned short*)p; p += (size_t)N_NODES*HID/2;
  float* hnext = p; p += (size_t)N_NODES*HID;
  float* excsr = p; p += (size_t)N_EDGES*NH;
  float* exself= p; p += (size_t)N_NODES*NH;
  float* a_s   = p; p += (size_t)N_NODES*NH;
  float* a_d   = p; p += (size_t)N_NODES*NH;
  float* easum = p; p += (size_t)N_NODES*3;
  float* wsrc  = p; p += NL*HID*NH;
  float* wdst  = p; p += NL*HID*NH;
  float* weatt = p; p += NL*3*NH;
  float* colsum= p; p += HID;
  float* colsq = p; p += HID;
  float* gsum  = p; p += NG*HID;
  float* gcnt  = p; p += NG;
  unsigned* gmaxenc = (unsigned*)p; p += NG*HID;
  int* degi    = (int*)p; p += N_NODES;
  int* rowptr  = (int*)p; p += (N_NODES + 1);
  int* fill    = (int*)p; p += N_NODES;
  int* blocksum= (int*)p; p += SCAN_NB;
  int* csr_src = (int*)p; p += N_EDGES;
  int* csr_pos = (int*)p; p += N_EDGES;
  int* csr_eid = (int*)p; p += N_EDGES;
  unsigned short* wt2  = (unsigned short*)p; p += NL*HID*HC/2;
  unsigned short* mw1  = (unsigned short*)p; p += 64*128/2;
  unsigned short* mw2  = (unsigned short*)p; p += 32*64/2;

  // once-per-call precompute
  hipMemsetAsync(degi, 0, (size_t)N_NODES*sizeof(int), stream);
  prep_att_kernel<<<NL, 128, 0, stream>>>(W, att_src, att_dst, We, att_e, wsrc, wdst, weatt);
  prep_wt2_kernel<<<dim3(65536/256, NL), 256, 0, stream>>>(W, wt2);
  prep_mlpw_kernel<<<32, 256, 0, stream>>>(nw1, nw2, mw1, mw2);
  xconv_kernel<<<(N_NODES*HID/4+255)/256, 256, 0, stream>>>(x, hb16);
  deg_kernel<<<(N_EDGES+255)/256, 256, 0, stream>>>(ei, degi);
  scan1_kernel<<<SCAN_NB, 1024, 0, stream>>>(degi, rowptr, fill, blocksum);
  scan2_kernel<<<SCAN_NB, 1024, 0, stream>>>(blocksum, rowptr);
  csr_fill_kernel<<<(N_EDGES+255)/256, 256, 0, stream>>>(ei, rowptr, fill, csr_src, csr_pos, csr_eid);
  easum_kernel<<<(N_NODES+255)/256, 256, 0, stream>>>(rowptr, csr_eid, ea, easum);
  asd_kernel<<<(N_NODES*64)/256, 256, 0, stream>>>(x, wsrc, wdst, a_s, a_d);   // layer-0 logits

  for (int l = 0; l < NL; ++l) {
    edge_ex_kernel<<<(N_TOT+255)/256, 256, 0, stream>>>(ei, ea, easum, rowptr, a_s, a_d,
                                                        weatt + l*3*NH, csr_pos, excsr, exself);
    agg_half_kernel<<<(N_NODES*64+255)/256, 256, 0, stream>>>(rowptr, csr_src, excsr, exself,
                                                              hb16, g16, colsum, colsq, 0);
    agg_half_kernel<<<(N_NODES*64+255)/256, 256, 0, stream>>>(rowptr, csr_src, excsr, exself,
                                                              hb16, g16, colsum, colsq, 64);
    gemm2_mfma_kernel<<<(N_NODES+63)/64, 256, 0, stream>>>(g16, wt2 + (size_t)l*65536,
                                                           hnext, colsum, colsq);
    if (l < NL-1) {
      bnasd_kernel<<<(N_NODES*64)/256, 256, 0, stream>>>(hnext, colsum, colsq,
                                                         gamma + l*HID, beta + l*HID,
                                                         wsrc + (l+1)*HID*NH, wdst + (l+1)*HID*NH,
                                                         hb16, a_s, a_d);
    } else {
      bnfinal_kernel<<<(N_NODES*HID/4+255)/256, 256, 0, stream>>>(hnext, colsum, colsq,
                                                                  gamma + l*HID, beta + l*HID, hb16);
    }
  }

  nodemlp_kernel<<<(N_NODES+127)/128, 256, 0, stream>>>(hb16, mw1, nb1, mw2, nb2, nw3, nb3, out,
                                                        gsum, gcnt, gmaxenc);
  pool_seg_kernel<<<(N_NODES + POOL_CHUNK - 1)/POOL_CHUNK, 128, 0, stream>>>(hb16, batch, gsum, gmaxenc, gcnt);
  graphmlp_kernel<<<NG, 128, 0, stream>>>(gsum, gmaxenc, gcnt, gw1, gb1, gw2, gb2, gw3, gb3, out);
}

// Round 20
// 428.672 us; speedup vs baseline: 1.0471x; 1.0471x over previous
//
#include <hip/hip_runtime.h>
#include <float.h>

#define N_NODES 30000
#define N_EDGES 400000
#define N_TOT   430000
#define HID     128
#define NH      4
#define HC      512
#define NL      3
#define NG      64
#define NEG_SLOPE 0.2f
#define BN_EPS 1e-5f
#define POOL_CHUNK 32
#define LDA_PAD 136
#define SCAN_NB ((N_NODES + 1023) / 1024)   // 30

typedef __attribute__((ext_vector_type(8))) short bf16x8;
typedef __attribute__((ext_vector_type(4))) float f32x4;

__device__ __forceinline__ float atomAddF(float* p, float v) { return unsafeAtomicAdd(p, v); }

__device__ __forceinline__ unsigned encf(float x) {
  unsigned u = __float_as_uint(x);
  return (u & 0x80000000u) ? ~u : (u | 0x80000000u);
}
__device__ __forceinline__ float decf(unsigned u) {
  return (u & 0x80000000u) ? __uint_as_float(u ^ 0x80000000u) : __uint_as_float(~u);
}
__device__ __forceinline__ unsigned short f2bf(float f) {   // RNE
  unsigned u = __float_as_uint(f);
  u += 0x7FFFu + ((u >> 16) & 1u);
  return (unsigned short)(u >> 16);
}
__device__ __forceinline__ float bf2f(unsigned short s) {
  return __uint_as_float(((unsigned)s) << 16);
}

__device__ __forceinline__ void accum_edge(float acc[4][4],
                                           float& d0, float& d1, float& d2, float& d3,
                                           float4 ex, ushort4 v) {
  float f0 = bf2f(v.x), f1 = bf2f(v.y), f2 = bf2f(v.z), f3 = bf2f(v.w);
  d0 += ex.x; d1 += ex.y; d2 += ex.z; d3 += ex.w;
  acc[0][0] = fmaf(ex.x, f0, acc[0][0]); acc[0][1] = fmaf(ex.x, f1, acc[0][1]);
  acc[0][2] = fmaf(ex.x, f2, acc[0][2]); acc[0][3] = fmaf(ex.x, f3, acc[0][3]);
  acc[1][0] = fmaf(ex.y, f0, acc[1][0]); acc[1][1] = fmaf(ex.y, f1, acc[1][1]);
  acc[1][2] = fmaf(ex.y, f2, acc[1][2]); acc[1][3] = fmaf(ex.y, f3, acc[1][3]);
  acc[2][0] = fmaf(ex.z, f0, acc[2][0]); acc[2][1] = fmaf(ex.z, f1, acc[2][1]);
  acc[2][2] = fmaf(ex.z, f2, acc[2][2]); acc[2][3] = fmaf(ex.z, f3, acc[2][3]);
  acc[3][0] = fmaf(ex.w, f0, acc[3][0]); acc[3][1] = fmaf(ex.w, f1, acc[3][1]);
  acc[3][2] = fmaf(ex.w, f2, acc[3][2]); acc[3][3] = fmaf(ex.w, f3, acc[3][3]);
}

// ---------------- attention projection precompute ----------------
__global__ void prep_att_kernel(const float* __restrict__ W, const float* __restrict__ att_src,
                                const float* __restrict__ att_dst, const float* __restrict__ We,
                                const float* __restrict__ att_e,
                                float* __restrict__ wsrc, float* __restrict__ wdst,
                                float* __restrict__ weatt) {
  int l = blockIdx.x, t = threadIdx.x;   // 128 threads
  for (int h = 0; h < NH; ++h) {
    const float* as = att_src + (size_t)(l*NH + h)*HID;
    const float* ad = att_dst + (size_t)(l*NH + h)*HID;
    const float* wr = W + (size_t)(l*HID + t)*HC + h*HID;
    float s = 0.f, d = 0.f;
    for (int c = 0; c < HID; ++c) { float w = wr[c]; s += w*as[c]; d += w*ad[c]; }
    wsrc[(l*HID + t)*NH + h] = s;
    wdst[(l*HID + t)*NH + h] = d;
  }
  if (t < 3) {
    for (int h = 0; h < NH; ++h) {
      const float* ae = att_e + (size_t)(l*NH + h)*HID;
      const float* wr = We + (size_t)(l*3 + t)*HC + h*HID;
      float s = 0.f;
      for (int c = 0; c < HID; ++c) s += wr[c]*ae[c];
      weatt[(l*3 + t)*NH + h] = s;
    }
  }
}

// Packed MFMA B-fragments for gemm2
__global__ void prep_wt2_kernel(const float* __restrict__ W, unsigned short* __restrict__ Wt2P) {
  int l = blockIdx.y;
  int idx = blockIdx.x*256 + threadIdx.x;   // over 65536
  int j    = idx & 7;
  int lane = (idx >> 3) & 63;
  int nf   = (idx >> 9) & 7;
  int kk   = idx >> 12;
  int co = nf*16 + (lane & 15);
  int k  = kk*32 + (lane >> 4)*8 + j;
  int h = k >> 7, ci = k & 127;
  Wt2P[(size_t)l*65536 + idx] = f2bf(0.25f * W[((size_t)l*HID + ci)*HC + h*128 + co]);
}

// node-MLP transposed bf16 weights
__global__ void prep_mlpw_kernel(const float* __restrict__ nw1, const float* __restrict__ nw2,
                                 unsigned short* __restrict__ wt1, unsigned short* __restrict__ wt2) {
  int t = blockIdx.x*256 + threadIdx.x;
  if (t < 64*128) {
    int n = t >> 7, k = t & 127;
    wt1[t] = f2bf(nw1[k*64 + n]);
  }
  if (t < 32*64) {
    int n = t >> 6, k = t & 63;
    wt2[t] = f2bf(nw2[k*32 + n]);
  }
}

// in-degree count
__global__ void deg_kernel(const int* __restrict__ ei, int* __restrict__ degi) {
  int e = blockIdx.x*blockDim.x + threadIdx.x;
  if (e >= N_EDGES) return;
  atomicAdd(&degi[ei[N_EDGES + e]], 1);
}

// ---------------- CSR build: two-phase multi-block exclusive scan ----------------
__global__ __launch_bounds__(1024) void scan1_kernel(const int* __restrict__ degi,
                                                     int* __restrict__ rowptr,
                                                     int* __restrict__ fill,
                                                     int* __restrict__ blocksum) {
  __shared__ int sh[1024];
  int b = blockIdx.x, t = threadIdx.x;
  int idx = b*1024 + t;
  int d = (idx < N_NODES) ? degi[idx] : 0;
  sh[t] = d;
  __syncthreads();
  for (int off = 1; off < 1024; off <<= 1) {
    int v = (t >= off) ? sh[t - off] : 0;
    __syncthreads();
    sh[t] += v;
    __syncthreads();
  }
  if (idx < N_NODES) {
    rowptr[idx] = sh[t] - d;
    fill[idx] = 0;
  }
  if (t == 1023) blocksum[b] = sh[1023];
}

__global__ __launch_bounds__(1024) void scan2_kernel(const int* __restrict__ blocksum,
                                                     int* __restrict__ rowptr) {
  int b = blockIdx.x, t = threadIdx.x;
  int off = 0;
  for (int i = 0; i < b; ++i) off += blocksum[i];
  int idx = b*1024 + t;
  if (idx < N_NODES && b > 0) rowptr[idx] += off;
  if (b == SCAN_NB - 1 && t == 1023)
    rowptr[N_NODES] = off + blocksum[SCAN_NB - 1];
}

__global__ void csr_fill_kernel(const int* __restrict__ ei, const int* __restrict__ rowptr,
                                int* __restrict__ fill, int* __restrict__ csr_src,
                                int* __restrict__ csr_pos, int* __restrict__ csr_eid) {
  int e = blockIdx.x*blockDim.x + threadIdx.x;
  if (e >= N_EDGES) return;
  int s = ei[e], d = ei[N_EDGES + e];
  int pos = rowptr[d] + atomicAdd(&fill[d], 1);
  csr_src[pos] = s;
  csr_pos[e] = pos;
  csr_eid[pos] = e;
}

// easum from CSR
__global__ void easum_kernel(const int* __restrict__ rowptr, const int* __restrict__ csr_eid,
                             const float* __restrict__ ea, float* __restrict__ easum) {
  int n = blockIdx.x*256 + threadIdx.x;
  if (n >= N_NODES) return;
  int p0 = rowptr[n], p1 = rowptr[n+1];
  float s0 = 0.f, s1 = 0.f, s2 = 0.f;
  for (int p = p0; p < p1; ++p) {
    int e = csr_eid[p];
    s0 += ea[e*3+0]; s1 += ea[e*3+1]; s2 += ea[e*3+2];
  }
  easum[n*3+0] = s0; easum[n*3+1] = s1; easum[n*3+2] = s2;
}

// ---------------- layer-0 a_s/a_d from f32 input; also emits bf16 h (xconv fused) ----------------
__global__ __launch_bounds__(256) void asd_kernel(const float* __restrict__ hin,
                                                  const float* __restrict__ wsrcL,
                                                  const float* __restrict__ wdstL,
                                                  float* __restrict__ a_s, float* __restrict__ a_d,
                                                  unsigned short* __restrict__ hb16) {
  int wid = (blockIdx.x*256 + threadIdx.x) >> 6;
  int lane = threadIdx.x & 63;
  if (wid >= N_NODES) return;
  float v0 = hin[(size_t)wid*HID + lane];
  float v1 = hin[(size_t)wid*HID + 64 + lane];
  hb16[(size_t)wid*HID + lane] = f2bf(v0);
  hb16[(size_t)wid*HID + 64 + lane] = f2bf(v1);
  float4 w0s = *(const float4*)&wsrcL[lane*4];
  float4 w1s = *(const float4*)&wsrcL[(64+lane)*4];
  float4 w0d = *(const float4*)&wdstL[lane*4];
  float4 w1d = *(const float4*)&wdstL[(64+lane)*4];
  float ps0 = v0*w0s.x + v1*w1s.x, ps1 = v0*w0s.y + v1*w1s.y;
  float ps2 = v0*w0s.z + v1*w1s.z, ps3 = v0*w0s.w + v1*w1s.w;
  float pd0 = v0*w0d.x + v1*w1d.x, pd1 = v0*w0d.y + v1*w1d.y;
  float pd2 = v0*w0d.z + v1*w1d.z, pd3 = v0*w0d.w + v1*w1d.w;
  #pragma unroll
  for (int off = 32; off > 0; off >>= 1) {
    ps0 += __shfl_xor(ps0, off); ps1 += __shfl_xor(ps1, off);
    ps2 += __shfl_xor(ps2, off); ps3 += __shfl_xor(ps3, off);
    pd0 += __shfl_xor(pd0, off); pd1 += __shfl_xor(pd1, off);
    pd2 += __shfl_xor(pd2, off); pd3 += __shfl_xor(pd3, off);
  }
  if (lane == 0) {
    *(float4*)&a_s[wid*4] = make_float4(ps0, ps1, ps2, ps3);
    *(float4*)&a_d[wid*4] = make_float4(pd0, pd1, pd2, pd3);
  }
}

// ---------------- edge pass ----------------
__global__ void edge_ex_kernel(const int* __restrict__ ei, const float* __restrict__ ea,
                               const float* __restrict__ easum, const int* __restrict__ rowptr,
                               const float* __restrict__ a_s, const float* __restrict__ a_d,
                               const float* __restrict__ weattL, const int* __restrict__ csr_pos,
                               float* __restrict__ excsr, float* __restrict__ exself) {
  int e = blockIdx.x*blockDim.x + threadIdx.x;
  if (e >= N_TOT) return;
  int s, d; float e0, e1, e2;
  if (e < N_EDGES) {
    s = ei[e]; d = ei[N_EDGES + e];
    e0 = ea[e*3+0]; e1 = ea[e*3+1]; e2 = ea[e*3+2];
  } else {
    int n = e - N_EDGES; s = n; d = n;
    float dg = (float)(rowptr[n+1] - rowptr[n]);
    float inv = 1.f / fmaxf(dg, 1.f);
    e0 = easum[n*3+0]*inv; e1 = easum[n*3+1]*inv; e2 = easum[n*3+2]*inv;
  }
  float4 as4 = *(const float4*)&a_s[s*4];
  float4 ad4 = *(const float4*)&a_d[d*4];
  float4 w0 = *(const float4*)&weattL[0];
  float4 w1 = *(const float4*)&weattL[4];
  float4 w2 = *(const float4*)&weattL[8];
  float raw0 = as4.x + ad4.x + e0*w0.x + e1*w1.x + e2*w2.x;
  float raw1 = as4.y + ad4.y + e0*w0.y + e1*w1.y + e2*w2.y;
  float raw2 = as4.z + ad4.z + e0*w0.z + e1*w1.z + e2*w2.z;
  float raw3 = as4.w + ad4.w + e0*w0.w + e1*w1.w + e2*w2.w;
  raw0 = raw0 > 0.f ? raw0 : NEG_SLOPE*raw0;
  raw1 = raw1 > 0.f ? raw1 : NEG_SLOPE*raw1;
  raw2 = raw2 > 0.f ? raw2 : NEG_SLOPE*raw2;
  raw3 = raw3 > 0.f ? raw3 : NEG_SLOPE*raw3;
  float4 exv = make_float4(__expf(raw0), __expf(raw1), __expf(raw2), __expf(raw3));
  if (e < N_EDGES) {
    *(float4*)&excsr[(size_t)csr_pos[e]*4] = exv;
  } else {
    *(float4*)&exself[(size_t)(e - N_EDGES)*4] = exv;
  }
}

// ---------------- CSR aggregation: wave per dst, 8-edge unroll (4 per half) ----------------
// block 0 also zeroes colsum/colsq for the following gemm2
__global__ __launch_bounds__(256) void agg_kernel(const int* __restrict__ rowptr,
    const int* __restrict__ csr_src, const float* __restrict__ excsr,
    const float* __restrict__ exself, const unsigned short* __restrict__ hb16,
    unsigned short* __restrict__ g16, float* __restrict__ colsum, float* __restrict__ colsq) {
  if (blockIdx.x == 0) {
    int tt = threadIdx.x;
    if (tt < 128) colsum[tt] = 0.f;
    else colsq[tt-128] = 0.f;
  }
  int wid = (blockIdx.x*256 + threadIdx.x) >> 6;
  int lane = threadIdx.x & 63;
  if (wid >= N_NODES) return;
  int half = lane >> 5, li = lane & 31;
  int c0 = li * 4;
  int p0 = rowptr[wid], p1 = rowptr[wid+1];
  float acc[4][4] = {};
  float den0 = 0.f, den1 = 0.f, den2 = 0.f, den3 = 0.f;
  if (half == 0) {            // self loop
    float4 ex = *(const float4*)&exself[(size_t)wid*4];
    ushort4 v = *(const ushort4*)&hb16[(size_t)wid*HID + c0];
    accum_edge(acc, den0, den1, den2, den3, ex, v);
  }
  int p = p0;
  for (; p + 8 <= p1; p += 8) {      // 4 edges per half, batched loads
    int base = p + half*4;
    int s0 = csr_src[base+0], s1 = csr_src[base+1], s2 = csr_src[base+2], s3 = csr_src[base+3];
    float4 e0 = *(const float4*)&excsr[(size_t)(base+0)*4];
    float4 e1 = *(const float4*)&excsr[(size_t)(base+1)*4];
    float4 e2 = *(const float4*)&excsr[(size_t)(base+2)*4];
    float4 e3 = *(const float4*)&excsr[(size_t)(base+3)*4];
    ushort4 v0 = *(const ushort4*)&hb16[(size_t)s0*HID + c0];
    ushort4 v1 = *(const ushort4*)&hb16[(size_t)s1*HID + c0];
    ushort4 v2 = *(const ushort4*)&hb16[(size_t)s2*HID + c0];
    ushort4 v3 = *(const ushort4*)&hb16[(size_t)s3*HID + c0];
    accum_edge(acc, den0, den1, den2, den3, e0, v0);
    accum_edge(acc, den0, den1, den2, den3, e1, v1);
    accum_edge(acc, den0, den1, den2, den3, e2, v2);
    accum_edge(acc, den0, den1, den2, den3, e3, v3);
  }
  for (; p + 2 <= p1; p += 2) {      // 1 edge per half
    int pe = p + half;
    int s = csr_src[pe];
    float4 ex = *(const float4*)&excsr[(size_t)pe*4];
    ushort4 v = *(const ushort4*)&hb16[(size_t)s*HID + c0];
    accum_edge(acc, den0, den1, den2, den3, ex, v);
  }
  if (p < p1 && half == 0) {         // odd tail
    int s = csr_src[p];
    float4 ex = *(const float4*)&excsr[(size_t)p*4];
    ushort4 v = *(const ushort4*)&hb16[(size_t)s*HID + c0];
    accum_edge(acc, den0, den1, den2, den3, ex, v);
  }
  #pragma unroll
  for (int h = 0; h < 4; ++h)
    #pragma unroll
    for (int j = 0; j < 4; ++j)
      acc[h][j] += __shfl_xor(acc[h][j], 32);
  den0 += __shfl_xor(den0, 32); den1 += __shfl_xor(den1, 32);
  den2 += __shfl_xor(den2, 32); den3 += __shfl_xor(den3, 32);
  float inv[4] = {1.f/den0, 1.f/den1, 1.f/den2, 1.f/den3};
  #pragma unroll
  for (int k = 0; k < 2; ++k) {
    int h = half*2 + k;
    ushort4 o;
    o.x = f2bf(acc[h][0]*inv[h]); o.y = f2bf(acc[h][1]*inv[h]);
    o.z = f2bf(acc[h][2]*inv[h]); o.w = f2bf(acc[h][3]*inv[h]);
    *(ushort4*)&g16[(size_t)wid*HC + h*128 + c0] = o;
  }
}

// ---------------- gemm2: LDS-staged packed B + fused BN stats ----------------
#define MFMA16(a, b, c) __builtin_amdgcn_mfma_f32_16x16x32_bf16(a, b, c, 0, 0, 0)

__global__ __launch_bounds__(256) void gemm2_mfma_kernel(const unsigned short* __restrict__ g16,
                                                         const unsigned short* __restrict__ Wt2P,
                                                         float* __restrict__ C,
                                                         float* __restrict__ colsum,
                                                         float* __restrict__ colsq) {
  __shared__ unsigned short Bs[4*8*512];     // 32 KB
  __shared__ float cs_s[128], cq_s[128];
  int m0 = blockIdx.x * 64;
  int t = threadIdx.x;
  int wave = t >> 6, lane = t & 63;
  int mbase = m0 + wave * 16;
  int lrow = lane & 15;
  if (t < 128) { cs_s[t] = 0.f; cq_s[t] = 0.f; }
  int arow = mbase + lrow;
  const unsigned short* arp = g16 + (size_t)(arow < N_NODES ? arow : 0)*HC + (lane >> 4)*8;
  f32x4 acc[8] = {};
  for (int ph = 0; ph < 4; ++ph) {
    const bf16x8* src = (const bf16x8*)(Wt2P + ph*16384);
    __syncthreads();
    #pragma unroll
    for (int i = 0; i < 8; ++i)
      *(bf16x8*)&Bs[(t + i*256)*8] = src[t + i*256];
    __syncthreads();
    #pragma unroll
    for (int kk = 0; kk < 4; ++kk) {
      bf16x8 a = *(const bf16x8*)&arp[(ph*4 + kk)*32];
      #pragma unroll
      for (int nf = 0; nf < 8; ++nf) {
        bf16x8 b = *(const bf16x8*)&Bs[(kk*8 + nf)*512 + lane*8];
        acc[nf] = MFMA16(a, b, acc[nf]);
      }
    }
  }
  int orow = (lane >> 4) * 4, ocol = lane & 15;
  #pragma unroll
  for (int nf = 0; nf < 8; ++nf) {
    float s = 0.f, q = 0.f;
    #pragma unroll
    for (int r = 0; r < 4; ++r) {
      int gm = mbase + orow + r;
      float v = acc[nf][r];
      if (gm < N_NODES) {
        C[(size_t)gm*HID + nf*16 + ocol] = v;
        s += v; q += v*v;
      }
    }
    atomicAdd(&cs_s[nf*16 + ocol], s);
    atomicAdd(&cq_s[nf*16 + ocol], q);
  }
  __syncthreads();
  if (t < 128) {
    atomAddF(&colsum[t], cs_s[t]);
    atomAddF(&colsq[t], cq_s[t]);
  }
}

// ---------------- fused BN-apply + next-layer a_s/a_d ----------------
__global__ __launch_bounds__(256) void bnasd_kernel(const float* __restrict__ hpre,
    const float* __restrict__ colsum, const float* __restrict__ colsq,
    const float* __restrict__ gammaL, const float* __restrict__ betaL,
    const float* __restrict__ wsrcL, const float* __restrict__ wdstL,
    unsigned short* __restrict__ hb16, float* __restrict__ a_s, float* __restrict__ a_d) {
  int wid = (blockIdx.x*256 + threadIdx.x) >> 6;
  int lane = threadIdx.x & 63;
  if (wid >= N_NODES) return;
  const float invn = 1.f / (float)N_NODES;
  float v0 = hpre[(size_t)wid*HID + lane];
  float v1 = hpre[(size_t)wid*HID + 64 + lane];
  float mu0 = colsum[lane]*invn, mu1 = colsum[64+lane]*invn;
  float var0 = fmaxf(colsq[lane]*invn - mu0*mu0, 0.f);
  float var1 = fmaxf(colsq[64+lane]*invn - mu1*mu1, 0.f);
  float sc0 = gammaL[lane]*rsqrtf(var0 + BN_EPS), sh0 = betaL[lane] - mu0*sc0;
  float sc1 = gammaL[64+lane]*rsqrtf(var1 + BN_EPS), sh1 = betaL[64+lane] - mu1*sc1;
  v0 = fmaxf(fmaf(v0, sc0, sh0), 0.f);
  v1 = fmaxf(fmaf(v1, sc1, sh1), 0.f);
  hb16[(size_t)wid*HID + lane] = f2bf(v0);
  hb16[(size_t)wid*HID + 64 + lane] = f2bf(v1);
  float4 w0s = *(const float4*)&wsrcL[lane*4];
  float4 w1s = *(const float4*)&wsrcL[(64+lane)*4];
  float4 w0d = *(const float4*)&wdstL[lane*4];
  float4 w1d = *(const float4*)&wdstL[(64+lane)*4];
  float ps0 = v0*w0s.x + v1*w1s.x, ps1 = v0*w0s.y + v1*w1s.y;
  float ps2 = v0*w0s.z + v1*w1s.z, ps3 = v0*w0s.w + v1*w1s.w;
  float pd0 = v0*w0d.x + v1*w1d.x, pd1 = v0*w0d.y + v1*w1d.y;
  float pd2 = v0*w0d.z + v1*w1d.z, pd3 = v0*w0d.w + v1*w1d.w;
  #pragma unroll
  for (int off = 32; off > 0; off >>= 1) {
    ps0 += __shfl_xor(ps0, off); ps1 += __shfl_xor(ps1, off);
    ps2 += __shfl_xor(ps2, off); ps3 += __shfl_xor(ps3, off);
    pd0 += __shfl_xor(pd0, off); pd1 += __shfl_xor(pd1, off);
    pd2 += __shfl_xor(pd2, off); pd3 += __shfl_xor(pd3, off);
  }
  if (lane == 0) {
    *(float4*)&a_s[wid*4] = make_float4(ps0, ps1, ps2, ps3);
    *(float4*)&a_d[wid*4] = make_float4(pd0, pd1, pd2, pd3);
  }
}

// ---------------- final-layer BN apply -> bf16 only ----------------
__global__ void bnfinal_kernel(const float* __restrict__ hpre,
                               const float* __restrict__ colsum, const float* __restrict__ colsq,
                               const float* __restrict__ gammaL, const float* __restrict__ betaL,
                               unsigned short* __restrict__ hb16) {
  int i = blockIdx.x*blockDim.x + threadIdx.x;
  if (i >= N_NODES*HID/4) return;
  int c4 = (i*4) & 127;
  const float invn = 1.f / (float)N_NODES;
  float4 v = *(const float4*)&hpre[(size_t)i*4];
  float4 cs = *(const float4*)&colsum[c4];
  float4 cq = *(const float4*)&colsq[c4];
  float4 gm = *(const float4*)&gammaL[c4];
  float4 bt = *(const float4*)&betaL[c4];
  float mu, var, sc, sh;
  mu = cs.x*invn; var = fmaxf(cq.x*invn - mu*mu, 0.f); sc = gm.x*rsqrtf(var + BN_EPS); sh = bt.x - mu*sc;
  v.x = fmaxf(fmaf(v.x, sc, sh), 0.f);
  mu = cs.y*invn; var = fmaxf(cq.y*invn - mu*mu, 0.f); sc = gm.y*rsqrtf(var + BN_EPS); sh = bt.y - mu*sc;
  v.y = fmaxf(fmaf(v.y, sc, sh), 0.f);
  mu = cs.z*invn; var = fmaxf(cq.z*invn - mu*mu, 0.f); sc = gm.z*rsqrtf(var + BN_EPS); sh = bt.z - mu*sc;
  v.z = fmaxf(fmaf(v.z, sc, sh), 0.f);
  mu = cs.w*invn; var = fmaxf(cq.w*invn - mu*mu, 0.f); sc = gm.w*rsqrtf(var + BN_EPS); sh = bt.w - mu*sc;
  v.w = fmaxf(fmaf(v.w, sc, sh), 0.f);
  ushort4 o; o.x = f2bf(v.x); o.y = f2bf(v.y); o.z = f2bf(v.z); o.w = f2bf(v.w);
  *(ushort4*)&hb16[(size_t)i*4] = o;
}

// ---------------- node MLP (block 0 also inits pooling buffers) ----------------
__global__ __launch_bounds__(256) void nodemlp_kernel(const unsigned short* __restrict__ h16,
    const unsigned short* __restrict__ wt1, const float* __restrict__ b1,
    const unsigned short* __restrict__ wt2, const float* __restrict__ b2,
    const float* __restrict__ w3, const float* __restrict__ b3,
    float* __restrict__ out,
    float* __restrict__ gsum, float* __restrict__ gcnt, unsigned* __restrict__ gmaxenc) {
  __shared__ unsigned short As[128 * LDA_PAD];
  __shared__ unsigned short L1s[128 * 72];
  __shared__ float L2s[128 * 33];
  int m0 = blockIdx.x * 128;
  int t = threadIdx.x;
  if (blockIdx.x == 0) {
    for (int i = t; i < NG*HID; i += 256) { gsum[i] = 0.f; gmaxenc[i] = 0x00800000u; }
    if (t < NG) gcnt[t] = 0.f;
  }
  #pragma unroll
  for (int i = 0; i < 8; ++i) {
    int idx = t + i*256;
    int row = idx >> 4, k8 = (idx & 15) * 8;
    int gm = m0 + row;
    bf16x8 v = {};
    if (gm < N_NODES) v = *(const bf16x8*)&h16[(size_t)gm*HID + k8];
    *(bf16x8*)&As[row*LDA_PAD + k8] = v;
  }
  __syncthreads();
  int wave = t >> 6, lane = t & 63;
  int mbase = wave * 32;
  int lrow = lane & 15, lk = (lane >> 4) * 8;
  int orow = (lane >> 4) * 4, ocol = lane & 15;
  // layer 1
  f32x4 acc[2][4] = {};
  #pragma unroll
  for (int ks = 0; ks < 4; ++ks) {
    int k0 = ks * 32;
    bf16x8 a0 = *(const bf16x8*)&As[(mbase + lrow)*LDA_PAD + k0 + lk];
    bf16x8 a1 = *(const bf16x8*)&As[(mbase + 16 + lrow)*LDA_PAD + k0 + lk];
    #pragma unroll
    for (int nf = 0; nf < 4; ++nf) {
      bf16x8 b = *(const bf16x8*)&wt1[(size_t)(nf*16 + lrow)*HID + k0 + lk];
      acc[0][nf] = MFMA16(a0, b, acc[0][nf]);
      acc[1][nf] = MFMA16(a1, b, acc[1][nf]);
    }
  }
  #pragma unroll
  for (int mf = 0; mf < 2; ++mf)
    #pragma unroll
    for (int nf = 0; nf < 4; ++nf) {
      float bb = b1[nf*16 + ocol];
      #pragma unroll
      for (int r = 0; r < 4; ++r)
        L1s[(mbase + mf*16 + orow + r)*72 + nf*16 + ocol] = f2bf(fmaxf(acc[mf][nf][r] + bb, 0.f));
    }
  __syncthreads();
  // layer 2
  f32x4 acc2[2][2] = {};
  #pragma unroll
  for (int ks = 0; ks < 2; ++ks) {
    int k0 = ks * 32;
    bf16x8 a0 = *(const bf16x8*)&L1s[(mbase + lrow)*72 + k0 + lk];
    bf16x8 a1 = *(const bf16x8*)&L1s[(mbase + 16 + lrow)*72 + k0 + lk];
    #pragma unroll
    for (int nf = 0; nf < 2; ++nf) {
      bf16x8 b = *(const bf16x8*)&wt2[(size_t)(nf*16 + lrow)*64 + k0 + lk];
      acc2[0][nf] = MFMA16(a0, b, acc2[0][nf]);
      acc2[1][nf] = MFMA16(a1, b, acc2[1][nf]);
    }
  }
  #pragma unroll
  for (int mf = 0; mf < 2; ++mf)
    #pragma unroll
    for (int nf = 0; nf < 2; ++nf) {
      float bb = b2[nf*16 + ocol];
      #pragma unroll
      for (int r = 0; r < 4; ++r)
        L2s[(mbase + mf*16 + orow + r)*33 + nf*16 + ocol] = fmaxf(acc2[mf][nf][r] + bb, 0.f);
    }
  __syncthreads();
  // layer 3
  {
    int node = t >> 1, j = t & 1;
    int gm = m0 + node;
    if (gm < N_NODES) {
      float accv = b3[j];
      #pragma unroll
      for (int k = 0; k < 32; ++k)
        accv = fmaf(L2s[node*33 + k], w3[k*2 + j], accv);
      out[(size_t)gm*2 + j] = accv;
    }
  }
}

// ---------------- graph pooling (segmented over sorted batch, bf16 input) ----------------
__global__ __launch_bounds__(128) void pool_seg_kernel(const unsigned short* __restrict__ h16,
                                                       const int* __restrict__ batch,
                                                       float* __restrict__ gsum,
                                                       unsigned* __restrict__ gmaxenc,
                                                       float* __restrict__ gcnt) {
  int t = threadIdx.x;
  int r0 = blockIdx.x * POOL_CHUNK;
  int rend = min(r0 + POOL_CHUNK, N_NODES);
  if (r0 >= N_NODES) return;
  int gcur = batch[r0];
  float s = 0.f, m = -FLT_MAX;
  int cnt = 0;
  for (int r = r0; r < rend; ++r) {
    int g = batch[r];
    if (g != gcur) {
      atomAddF(&gsum[gcur*HID + t], s);
      atomicMax(&gmaxenc[gcur*HID + t], encf(m));
      if (t == 0) atomAddF(&gcnt[gcur], (float)cnt);
      gcur = g; s = 0.f; m = -FLT_MAX; cnt = 0;
    }
    float v = bf2f(h16[(size_t)r*HID + t]);
    s += v; m = fmaxf(m, v);
    ++cnt;
  }
  atomAddF(&gsum[gcur*HID + t], s);
  atomicMax(&gmaxenc[gcur*HID + t], encf(m));
  if (t == 0) atomAddF(&gcnt[gcur], (float)cnt);
}

// ---------------- graph MLP ----------------
__global__ __launch_bounds__(128) void graphmlp_kernel(const float* __restrict__ gsum,
    const unsigned* __restrict__ gmaxenc, const float* __restrict__ gcnt,
    const float* __restrict__ gw1, const float* __restrict__ gb1,
    const float* __restrict__ gw2, const float* __restrict__ gb2,
    const float* __restrict__ gw3, const float* __restrict__ gb3,
    float* __restrict__ out) {
  __shared__ float gr[256], h1[128], h2[64];
  int g = blockIdx.x, t = threadIdx.x;
  float cnt = fmaxf(gcnt[g], 1.f);
  gr[t] = gsum[g*HID + t] / cnt;
  gr[128 + t] = decf(gmaxenc[g*HID + t]);
  __syncthreads();
  float acc = gb1[t];
  for (int k = 0; k < 256; ++k) acc += gr[k]*gw1[k*HID + t];
  h1[t] = fmaxf(acc, 0.f);
  __syncthreads();
  if (t < 64) {
    float a2 = gb2[t];
    for (int k = 0; k < 128; ++k) a2 += h1[k]*gw2[k*64 + t];
    h2[t] = fmaxf(a2, 0.f);
  }
  __syncthreads();
  if (t < 2) {
    float a3 = gb3[t];
    for (int k = 0; k < 64; ++k) a3 += h2[k]*gw3[k*2 + t];
    out[N_NODES*2 + g*2 + t] = a3;
  }
}

extern "C" void kernel_launch(void* const* d_in, const int* in_sizes, int n_in,
                              void* d_out, int out_size, void* d_ws, size_t ws_size,
                              hipStream_t stream) {
  (void)in_sizes; (void)n_in; (void)out_size; (void)ws_size;
  const float* x       = (const float*)d_in[0];
  const int*   ei      = (const int*)d_in[1];
  const float* ea      = (const float*)d_in[2];
  const int*   batch   = (const int*)d_in[3];
  const float* W       = (const float*)d_in[4];
  const float* att_src = (const float*)d_in[5];
  const float* att_dst = (const float*)d_in[6];
  const float* We      = (const float*)d_in[7];
  const float* att_e   = (const float*)d_in[8];
  const float* gamma   = (const float*)d_in[10];
  const float* beta    = (const float*)d_in[11];
  const float* nw1 = (const float*)d_in[12]; const float* nb1 = (const float*)d_in[13];
  const float* nw2 = (const float*)d_in[14]; const float* nb2 = (const float*)d_in[15];
  const float* nw3 = (const float*)d_in[16]; const float* nb3 = (const float*)d_in[17];
  const float* gw1 = (const float*)d_in[18]; const float* gb1 = (const float*)d_in[19];
  const float* gw2 = (const float*)d_in[20]; const float* gb2 = (const float*)d_in[21];
  const float* gw3 = (const float*)d_in[22]; const float* gb3 = (const float*)d_in[23];
  float* out = (float*)d_out;

  float* p = (float*)d_ws;
  unsigned short* g16 = (unsigned short*)p; p += (size_t)N_NODES*HC/2;
  unsigned short* hb16= (unsigned short*)p; p += (size_t)N_NODES*HID/2;
  float* hnext = p; p += (size_t)N_NODES*HID;
  float* excsr = p; p += (size_t)N_EDGES*NH;
  float* exself= p; p += (size_t)N_NODES*NH;
  float* a_s   = p; p += (size_t)N_NODES*NH;
  float* a_d   = p; p += (size_t)N_NODES*NH;
  float* easum = p; p += (size_t)N_NODES*3;
  float* wsrc  = p; p += NL*HID*NH;
  float* wdst  = p; p += NL*HID*NH;
  float* weatt = p; p += NL*3*NH;
  float* colsum= p; p += HID;
  float* colsq = p; p += HID;
  float* gsum  = p; p += NG*HID;
  float* gcnt  = p; p += NG;
  unsigned* gmaxenc = (unsigned*)p; p += NG*HID;
  int* degi    = (int*)p; p += N_NODES;
  int* rowptr  = (int*)p; p += (N_NODES + 1);
  int* fill    = (int*)p; p += N_NODES;
  int* blocksum= (int*)p; p += SCAN_NB;
  int* csr_src = (int*)p; p += N_EDGES;
  int* csr_pos = (int*)p; p += N_EDGES;
  int* csr_eid = (int*)p; p += N_EDGES;
  unsigned short* wt2  = (unsigned short*)p; p += NL*HID*HC/2;
  unsigned short* mw1  = (unsigned short*)p; p += 64*128/2;
  unsigned short* mw2  = (unsigned short*)p; p += 32*64/2;

  // once-per-call precompute
  hipMemsetAsync(degi, 0, (size_t)N_NODES*sizeof(int), stream);
  prep_att_kernel<<<NL, 128, 0, stream>>>(W, att_src, att_dst, We, att_e, wsrc, wdst, weatt);
  prep_wt2_kernel<<<dim3(65536/256, NL), 256, 0, stream>>>(W, wt2);
  prep_mlpw_kernel<<<32, 256, 0, stream>>>(nw1, nw2, mw1, mw2);
  deg_kernel<<<(N_EDGES+255)/256, 256, 0, stream>>>(ei, degi);
  scan1_kernel<<<SCAN_NB, 1024, 0, stream>>>(degi, rowptr, fill, blocksum);
  scan2_kernel<<<SCAN_NB, 1024, 0, stream>>>(blocksum, rowptr);
  csr_fill_kernel<<<(N_EDGES+255)/256, 256, 0, stream>>>(ei, rowptr, fill, csr_src, csr_pos, csr_eid);
  easum_kernel<<<(N_NODES+255)/256, 256, 0, stream>>>(rowptr, csr_eid, ea, easum);
  asd_kernel<<<(N_NODES*64)/256, 256, 0, stream>>>(x, wsrc, wdst, a_s, a_d, hb16); // logits + bf16 x

  for (int l = 0; l < NL; ++l) {
    edge_ex_kernel<<<(N_TOT+255)/256, 256, 0, stream>>>(ei, ea, easum, rowptr, a_s, a_d,
                                                        weatt + l*3*NH, csr_pos, excsr, exself);
    agg_kernel<<<(N_NODES*64+255)/256, 256, 0, stream>>>(rowptr, csr_src, excsr, exself, hb16, g16,
                                                         colsum, colsq);
    gemm2_mfma_kernel<<<(N_NODES+63)/64, 256, 0, stream>>>(g16, wt2 + (size_t)l*65536,
                                                           hnext, colsum, colsq);
    if (l < NL-1) {
      bnasd_kernel<<<(N_NODES*64)/256, 256, 0, stream>>>(hnext, colsum, colsq,
                                                         gamma + l*HID, beta + l*HID,
                                                         wsrc + (l+1)*HID*NH, wdst + (l+1)*HID*NH,
                                                         hb16, a_s, a_d);
    } else {
      bnfinal_kernel<<<(N_NODES*HID/4+255)/256, 256, 0, stream>>>(hnext, colsum, colsq,
                                                                  gamma + l*HID, beta + l*HID, hb16);
    }
  }

  nodemlp_kernel<<<(N_NODES+127)/128, 256, 0, stream>>>(hb16, mw1, nb1, mw2, nb2, nw3, nb3, out,
                                                        gsum, gcnt, gmaxenc);
  pool_seg_kernel<<<(N_NODES + POOL_CHUNK - 1)/POOL_CHUNK, 128, 0, stream>>>(hb16, batch, gsum, gmaxenc, gcnt);
  graphmlp_kernel<<<NG, 128, 0, stream>>>(gsum, gmaxenc, gcnt, gw1, gb1, gw2, gb2, gw3, gb3, out);
}